// Round 12
// baseline (168.306 us; speedup 1.0000x reference)
//
#include <hip/hip_runtime.h>

#define N_ 256
#define C_ 2048
#define HW_ 49
#define CPB 64
#define NCC 32
#define NCHUNK 8
#define NBLK 1280       // persistent blocks (5/CU); tiles = 32cc x 256n = 8192

// ---------------- kernel 1: channel-pool partials (r8, at BW floor) ----------------
__global__ __launch_bounds__(256) void k_poolc(const float* __restrict__ x,
                                               float* __restrict__ psum,
                                               float* __restrict__ pmax) {
  const int bc = blockIdx.x, n = blockIdx.y;
  const int t = threadIdx.x;
  __shared__ __align__(16) float sx[CPB * HW_];
  __shared__ float part_s[HW_][5];
  __shared__ float part_m[HW_][5];

  float sm = 0.f, mx = -3.4e38f;
  const int hw = t / 5, s = t % 5;

  const float4* xv = (const float4*)(x + ((size_t)n * C_ + (size_t)bc * 256) * HW_);
  #pragma unroll
  for (int pass = 0; pass < 4; ++pass) {
    float4* sv = (float4*)sx;
    for (int v = t; v < 784; v += 256) sv[v] = xv[pass * 784 + v];
    __syncthreads();
    if (t < 245) {
      #pragma unroll
      for (int j = 0; j < 13; ++j) {
        int c = s * 13 + j;
        if (c < CPB) { float a = sx[c * HW_ + hw]; sm += a; mx = fmaxf(mx, a); }
      }
    }
    __syncthreads();
  }
  if (t < 245) { part_s[hw][s] = sm; part_m[hw][s] = mx; }
  __syncthreads();
  if (t < HW_) {
    float s2 = 0.f, m2 = -3.4e38f;
    #pragma unroll
    for (int k = 0; k < 5; ++k) { s2 += part_s[t][k]; m2 = fmaxf(m2, part_m[t][k]); }
    size_t o = ((size_t)n * NCHUNK + bc) * HW_ + t;
    psum[o] = s2; pmax[o] = m2;
  }
}

// ---------------- kernel 2: reduce partials, g_hw gate per n ----------------
__global__ __launch_bounds__(64) void k_ghw(const float* __restrict__ psum,
                                            const float* __restrict__ pmax,
                                            const float* __restrict__ cw,
                                            const float* __restrict__ cb,
                                            const float* __restrict__ bnw,
                                            const float* __restrict__ bnb,
                                            const float* __restrict__ bnrm,
                                            const float* __restrict__ bnrv,
                                            float* __restrict__ ghw) {
  const int n = blockIdx.x;
  const int t = threadIdx.x;
  __shared__ float p2c[2][13][13];
  __shared__ float s_cw[98];

  for (int i = t; i < 2 * 13 * 13; i += 64) ((float*)p2c)[i] = 0.f;
  for (int i = t; i < 98; i += 64) s_cw[i] = cw[i];
  __syncthreads();

  if (t < HW_) {
    float sm = 0.f, mx = -3.4e38f;
    const float* ps = psum + (size_t)n * NCHUNK * HW_ + t;
    const float* pm = pmax + (size_t)n * NCHUNK * HW_ + t;
    #pragma unroll
    for (int cc = 0; cc < NCHUNK; ++cc) {
      sm += ps[cc * HW_];
      mx = fmaxf(mx, pm[cc * HW_]);
    }
    p2c[0][t / 7 + 3][t % 7 + 3] = sm * (1.f / C_);
    p2c[1][t / 7 + 3][t % 7 + 3] = mx;
  }
  __syncthreads();

  if (t < HW_) {
    int a = t / 7, b = t % 7;
    float y = cb[0];
    #pragma unroll
    for (int i2 = 0; i2 < 2; ++i2)
      #pragma unroll
      for (int p = 0; p < 7; ++p)
        #pragma unroll
        for (int q = 0; q < 7; ++q)
          y += p2c[i2][a + p][b + q] * s_cw[i2 * 49 + p * 7 + q];
    float sc = bnw[0] * rsqrtf(bnrv[0] + 1e-5f);
    y = (y - bnrm[0]) * sc + bnb[0];
    y = fmaxf(y, 0.f);
    ghw[n * HW_ + t] = 1.f / (1.f + __expf(-y));
  }
}

// ---------------- kernel 3: persistent fused gates + multiply ----------------

__device__ __forceinline__ void pool_write(float* pool_lo, float* pool_hi, int row,
    const float* ws, const float* wm, const float* hs, const float* hm) {
  const float C7 = 1.f / 7.f;
  *(float4*)(pool_lo + (0 * 70 + row) * 4) = make_float4(ws[0]*C7, ws[1]*C7, ws[2]*C7, ws[3]*C7);
  *(float4*)(pool_hi + (0 * 70 + row) * 4) = make_float4(ws[4]*C7, ws[5]*C7, ws[6]*C7, 0.f);
  *(float4*)(pool_lo + (1 * 70 + row) * 4) = make_float4(wm[0], wm[1], wm[2], wm[3]);
  *(float4*)(pool_hi + (1 * 70 + row) * 4) = make_float4(wm[4], wm[5], wm[6], 0.f);
  *(float4*)(pool_lo + (2 * 70 + row) * 4) = make_float4(hs[0]*C7, hs[1]*C7, hs[2]*C7, hs[3]*C7);
  *(float4*)(pool_hi + (2 * 70 + row) * 4) = make_float4(hs[4]*C7, hs[5]*C7, hs[6]*C7, 0.f);
  *(float4*)(pool_lo + (3 * 70 + row) * 4) = make_float4(hm[0], hm[1], hm[2], hm[3]);
  *(float4*)(pool_hi + (3 * 70 + row) * 4) = make_float4(hm[4], hm[5], hm[6], 0.f);
}

__device__ __forceinline__ void pools_phase(const float* __restrict__ x,
    const float* sx, float* pool_lo, float* pool_hi, int t, int cc, int n) {
  if (t < 64) {
    // own channel from LDS: 13 conflict-free b128 (bank-start 20t%32)
    const float4* chp = (const float4*)(sx + t * 52);
    float ws[7], wm[7], hs[7], hm[7];
    #pragma unroll
    for (int r = 0; r < 7; ++r) { ws[r] = 0.f; wm[r] = -3.4e38f; hs[r] = 0.f; hm[r] = -3.4e38f; }
    #pragma unroll
    for (int b = 0; b < 13; ++b) {
      float4 q = chp[b];
      float vv[4] = {q.x, q.y, q.z, q.w};
      #pragma unroll
      for (int j = 0; j < 4; ++j) {
        int p = b * 4 + j;                    // compile-time after unroll
        if (p < 49) {
          int r = p / 7, k = p % 7;
          ws[r] += vv[j]; wm[r] = fmaxf(wm[r], vv[j]);
          hs[k] += vv[j]; hm[k] = fmaxf(hm[k], vv[j]);
        }
      }
    }
    pool_write(pool_lo, pool_hi, t + 3, ws, wm, hs, hm);
  } else if (t < 70) {
    // halo channel pools direct from global (L3-hot); zero outside [0,C)
    int hc = t - 64;
    int row = (hc < 3) ? hc : (64 + hc);      // 0..2, 67..69
    int c = (hc < 3) ? (cc * CPB - 3 + hc) : (cc * CPB + CPB + hc - 3);
    bool ok = (c >= 0 && c < C_);
    float ws[7], wm[7], hs[7], hm[7];
    #pragma unroll
    for (int r = 0; r < 7; ++r) {
      ws[r] = 0.f; hs[r] = 0.f;
      wm[r] = ok ? -3.4e38f : 0.f; hm[r] = ok ? -3.4e38f : 0.f;
    }
    if (ok) {
      const float* xp = x + ((size_t)n * C_ + c) * HW_;
      #pragma unroll
      for (int j = 0; j < 49; ++j) {
        int r = j / 7, k = j % 7;             // static
        float v = xp[j];
        ws[r] += v; wm[r] = fmaxf(wm[r], v);
        hs[k] += v; hm[k] = fmaxf(hm[k], v);
      }
    }
    pool_write(pool_lo, pool_hi, row, ws, wm, hs, hm);
  }
}

__device__ __forceinline__ void conv_phase(const float* pool_lo, const float* pool_hi,
    const float* s_w, float* gch, float* gcw, int conv, int i2, int cl,
    float cb0, float sc_bn, float rm_bn, float sh_bn) {
  const int f = conv * 2 + i2;
  const float* Wb = s_w + i2 * 56;
  float acc[7] = {0.f, 0.f, 0.f, 0.f, 0.f, 0.f, 0.f};
  #pragma unroll
  for (int p = 0; p < 7; ++p) {
    int ri = (f * 70 + cl + p) * 4;
    float4 r0 = *(const float4*)(pool_lo + ri);
    float4 r1 = *(const float4*)(pool_hi + ri);
    float row[7] = {r0.x, r0.y, r0.z, r0.w, r1.x, r1.y, r1.z};
    float4 w0 = *(const float4*)(Wb + p * 8);
    float4 w1 = *(const float4*)(Wb + p * 8 + 4);
    float wr[7] = {w0.x, w0.y, w0.z, w0.w, w1.x, w1.y, w1.z};
    #pragma unroll
    for (int q = 0; q < 7; ++q)
      #pragma unroll
      for (int k = 0; k < 7; ++k) {
        int c = k + q - 3;                    // compile-time after unroll
        if (c >= 0 && c < 7) acc[k] += row[c] * wr[q];
      }
  }
  float fsum[7];
  #pragma unroll
  for (int k = 0; k < 7; ++k) fsum[k] = acc[k] + __shfl_xor(acc[k], 2, 64);
  if (i2 == 0) {
    float* gp = (conv ? gcw : gch) + cl * 7;
    #pragma unroll
    for (int k = 0; k < 7; ++k) {
      float y = (fsum[k] + cb0 - rm_bn) * sc_bn + sh_bn;
      y = fmaxf(y, 0.f);
      gp[k] = 1.f / (1.f + __expf(-y));
    }
  }
}

__global__ __launch_bounds__(256, 5) void k_fused(const float* __restrict__ x,
    const float* __restrict__ ghw_g,
    const float* __restrict__ cw, const float* __restrict__ cb,
    const float* __restrict__ bnw, const float* __restrict__ bnb,
    const float* __restrict__ bnrm, const float* __restrict__ bnrv,
    float* __restrict__ out) {
  const int bid = blockIdx.x;
  const int t   = threadIdx.x;

  __shared__ __align__(16) float sx[64 * 52];    // channel-major, stride 52
  __shared__ __align__(16) float pool_lo[1120];  // [4][70][4] k=0..3
  __shared__ __align__(16) float pool_hi[1120];  // [4][70][4] k=4..6 (+dead pad)
  __shared__ __align__(16) float s_w[112];       // [2][7][8]
  __shared__ float gch[448];                     // [64][7]
  __shared__ float gcw[448];
  __shared__ float sg[2][49];                    // double-buffered ghw slice

  const int conv = t & 1, i2 = (t >> 1) & 1, cl = t >> 2;
  const int bi = 1 + conv;
  const float cb0 = cb[0];
  const float sc_bn = bnw[bi] * rsqrtf(bnrv[bi] + 1e-5f);
  const float rm_bn = bnrm[bi];
  const float sh_bn = bnb[bi];

  if (t < 112) {
    int i2w = t / 56, rem = t % 56, p = rem / 8, q = rem % 8;
    s_w[t] = (q < 7) ? cw[i2w * 49 + p * 7 + q] : 0.f;
  }

  float4 a0, a1, a2, a3, b0, b1, b2, b3;
  float ga, gb;

#define LOADT(TID, Q0, Q1, Q2, Q3, G) { \
    int cc_ = (TID) & 31, n_ = (TID) >> 5; \
    const float4* xv_ = (const float4*)(x + ((size_t)n_ * C_ + cc_ * CPB) * HW_); \
    Q0 = xv_[t]; Q1 = xv_[t + 256]; Q2 = xv_[t + 512]; \
    if (t < 16) Q3 = xv_[t + 768]; \
    if (t < HW_) G = ghw_g[n_ * HW_ + t]; }

#define ST4(Q, V) { \
    int e_ = (V) * 4; int ch_ = e_ / 49; int pos_ = e_ - ch_ * 49; \
    int ba_ = ch_ * 52 + pos_; \
    sx[ba_] = Q.x; \
    sx[ba_ + 1 + ((pos_ >= 48) ? 3 : 0)] = Q.y; \
    sx[ba_ + 2 + ((pos_ >= 47) ? 3 : 0)] = Q.z; \
    sx[ba_ + 3 + ((pos_ >= 46) ? 3 : 0)] = Q.w; }

#define WRITET(Q0, Q1, Q2, Q3, G, SGI) { \
    ST4(Q0, t); ST4(Q1, t + 256); ST4(Q2, t + 512); \
    if (t < 16) ST4(Q3, t + 768); \
    if (t < HW_) sg[SGI][t] = G; }

#define MUL1(Q, V) { \
    int e0_ = (V) * 4; int cj_ = e0_ / 49; int hw0_ = e0_ - cj_ * 49; \
    float r_[4] = {Q.x, Q.y, Q.z, Q.w}; \
    _Pragma("unroll") \
    for (int j = 0; j < 4; ++j) { \
      int hw_ = hw0_ + j; int cjj_ = cj_ + (hw_ >= 49); \
      hw_ -= (hw_ >= 49) ? 49 : 0; \
      int h_ = (hw_ * 37) >> 8, w2_ = hw_ - h_ * 7; \
      r_[j] *= (sgc[hw_] + gch[cjj_ * 7 + h_] + gcw[cjj_ * 7 + w2_]) * (1.f / 3.f); \
    } \
    outv[V] = make_float4(r_[0], r_[1], r_[2], r_[3]); }

#define ITER(IT, QC0, QC1, QC2, QC3, QN0, QN1, QN2, QN3, GN, SGC, SGN, HASN) { \
    const int tcur = bid + (IT) * NBLK; \
    const int cc_c = tcur & 31, n_c = tcur >> 5; \
    if (HASN) LOADT(bid + ((IT) + 1) * NBLK, QN0, QN1, QN2, QN3, GN); \
    pools_phase(x, sx, pool_lo, pool_hi, t, cc_c, n_c); \
    __syncthreads(); \
    conv_phase(pool_lo, pool_hi, s_w, gch, gcw, conv, i2, cl, cb0, sc_bn, rm_bn, sh_bn); \
    __syncthreads(); \
    { const float* sgc = sg[SGC]; \
      float4* outv = (float4*)(out + ((size_t)n_c * C_ + cc_c * CPB) * HW_); \
      MUL1(QC0, t); MUL1(QC1, t + 256); MUL1(QC2, t + 512); \
      if (t < 16) MUL1(QC3, t + 768); } \
    if (HASN) WRITET(QN0, QN1, QN2, QN3, GN, SGN); \
    __syncthreads(); }

  // prologue: tile bid -> regs A -> LDS
  LOADT(bid, a0, a1, a2, a3, ga);
  WRITET(a0, a1, a2, a3, ga, 0);
  __syncthreads();

  ITER(0, a0, a1, a2, a3, b0, b1, b2, b3, gb, 0, 1, true);
  ITER(1, b0, b1, b2, b3, a0, a1, a2, a3, ga, 1, 0, true);
  ITER(2, a0, a1, a2, a3, b0, b1, b2, b3, gb, 0, 1, true);
  ITER(3, b0, b1, b2, b3, a0, a1, a2, a3, ga, 1, 0, true);
  ITER(4, a0, a1, a2, a3, b0, b1, b2, b3, gb, 0, 1, true);
  ITER(5, b0, b1, b2, b3, a0, a1, a2, a3, ga, 1, 0, (bid < 512));
  if (bid < 512) {
    ITER(6, a0, a1, a2, a3, b0, b1, b2, b3, gb, 0, 1, false);
  }

#undef LOADT
#undef ST4
#undef WRITET
#undef MUL1
#undef ITER
}

extern "C" void kernel_launch(void* const* d_in, const int* in_sizes, int n_in,
                              void* d_out, int out_size, void* d_ws, size_t ws_size,
                              hipStream_t stream) {
  const float* x    = (const float*)d_in[0];
  const float* cw   = (const float*)d_in[1];
  const float* cb   = (const float*)d_in[2];
  const float* bnw  = (const float*)d_in[3];
  const float* bnb  = (const float*)d_in[4];
  const float* bnrm = (const float*)d_in[5];
  const float* bnrv = (const float*)d_in[6];
  float* out = (float*)d_out;

  float* psum = (float*)d_ws;                          // N*8*49
  float* pmax = psum + (size_t)N_ * NCHUNK * HW_;      // N*8*49
  float* ghw  = pmax + (size_t)N_ * NCHUNK * HW_;      // N*49

  k_poolc<<<dim3(NCHUNK, N_), 256, 0, stream>>>(x, psum, pmax);
  k_ghw<<<dim3(N_), 64, 0, stream>>>(psum, pmax, cw, cb, bnw, bnb, bnrm, bnrv, ghw);
  k_fused<<<dim3(NBLK), 256, 0, stream>>>(x, ghw, cw, cb, bnw, bnb, bnrm, bnrv, out);
}

// Round 13
// 79.027 us; speedup vs baseline: 2.1297x; 2.1297x over previous
//
#include <hip/hip_runtime.h>

#define N_ 256
#define C_ 2048
#define HW_ 49
#define CPB 64
#define NCC 32          // 64-ch chunks in k_main
#define NCHUNK 8        // 256-ch chunks in k_poolc

// local-channel base in sx: 70 channels (3 halo low, 64 main, 3 halo high).
// Main chunk starts at 148 (16B-aligned for float4); halo-low at 0, gap at 147.
#define CHB(lc) ((lc) * HW_ + ((lc) >= 3 ? 1 : 0))

// ---------------- kernel 1: channel-pool partials, 256 ch per block (r8) ----------------
__global__ __launch_bounds__(256) void k_poolc(const float* __restrict__ x,
                                               float* __restrict__ psum,
                                               float* __restrict__ pmax) {
  const int bc = blockIdx.x, n = blockIdx.y;
  const int t = threadIdx.x;
  __shared__ __align__(16) float sx[CPB * HW_];   // one 64-ch pass
  __shared__ float part_s[HW_][5];
  __shared__ float part_m[HW_][5];

  float sm = 0.f, mx = -3.4e38f;                  // carried across passes
  const int hw = t / 5, s = t % 5;

  const float4* xv = (const float4*)(x + ((size_t)n * C_ + (size_t)bc * 256) * HW_);
  #pragma unroll
  for (int pass = 0; pass < 4; ++pass) {
    float4* sv = (float4*)sx;
    for (int v = t; v < 784; v += 256) sv[v] = xv[pass * 784 + v];
    __syncthreads();
    if (t < 245) {
      #pragma unroll
      for (int j = 0; j < 13; ++j) {
        int c = s * 13 + j;
        if (c < CPB) {
          float a = sx[c * HW_ + hw];
          sm += a; mx = fmaxf(mx, a);
        }
      }
    }
    __syncthreads();
  }
  if (t < 245) { part_s[hw][s] = sm; part_m[hw][s] = mx; }
  __syncthreads();
  if (t < HW_) {
    float s2 = 0.f, m2 = -3.4e38f;
    #pragma unroll
    for (int k = 0; k < 5; ++k) { s2 += part_s[t][k]; m2 = fmaxf(m2, part_m[t][k]); }
    size_t o = ((size_t)n * NCHUNK + bc) * HW_ + t;
    psum[o] = s2; pmax[o] = m2;
  }
}

// ---------------- kernel 2: reduce chunks, compute g_hw gate per n ----------------
__global__ __launch_bounds__(64) void k_ghw(const float* __restrict__ psum,
                                            const float* __restrict__ pmax,
                                            const float* __restrict__ cw,
                                            const float* __restrict__ cb,
                                            const float* __restrict__ bnw,
                                            const float* __restrict__ bnb,
                                            const float* __restrict__ bnrm,
                                            const float* __restrict__ bnrv,
                                            float* __restrict__ ghw) {
  const int n = blockIdx.x;
  const int t = threadIdx.x;
  __shared__ float p2c[2][13][13];
  __shared__ float s_cw[98];

  for (int i = t; i < 2 * 13 * 13; i += 64) ((float*)p2c)[i] = 0.f;
  for (int i = t; i < 98; i += 64) s_cw[i] = cw[i];
  __syncthreads();

  if (t < HW_) {
    float sm = 0.f, mx = -3.4e38f;
    const float* ps = psum + (size_t)n * NCHUNK * HW_ + t;
    const float* pm = pmax + (size_t)n * NCHUNK * HW_ + t;
    #pragma unroll
    for (int cc = 0; cc < NCHUNK; ++cc) {
      sm += ps[cc * HW_];
      mx = fmaxf(mx, pm[cc * HW_]);
    }
    p2c[0][t / 7 + 3][t % 7 + 3] = sm * (1.f / C_);
    p2c[1][t / 7 + 3][t % 7 + 3] = mx;
  }
  __syncthreads();

  if (t < HW_) {
    int a = t / 7, b = t % 7;
    float y = cb[0];
    #pragma unroll
    for (int i2 = 0; i2 < 2; ++i2)
      #pragma unroll
      for (int p = 0; p < 7; ++p)
        #pragma unroll
        for (int q = 0; q < 7; ++q)
          y += p2c[i2][a + p][b + q] * s_cw[i2 * 49 + p * 7 + q];
    float sc = bnw[0] * rsqrtf(bnrv[0] + 1e-5f);
    y = (y - bnrm[0]) * sc + bnb[0];
    y = fmaxf(y, 0.f);
    ghw[n * HW_ + t] = 1.f / (1.f + __expf(-y));
  }
}

// ---------------- kernel 3: W/H pools, g_ch/g_cw gates, fused multiply (r7) ----------------
// LDS: sx[3432] + pool_lo[1120] + pool_hi[1120] + gch[448] + gcw[448]
//      + s_w[112] + s_ghw[49] = 6729 floats = 26.9 KB -> 6 blocks/CU.
// Pool rows are 16B (4 floats): b128 bank-start = 4*lc%32 -> 8 distinct starts.
__global__ __launch_bounds__(256, 6) void k_main(const float* __restrict__ x,
    const float* __restrict__ ghw,
    const float* __restrict__ cw, const float* __restrict__ cb,
    const float* __restrict__ bnw, const float* __restrict__ bnb,
    const float* __restrict__ bnrm, const float* __restrict__ bnrv,
    float* __restrict__ out) {
  const int cc = blockIdx.x;
  const int n  = (N_ - 1) - blockIdx.y;
  const int c0 = cc * CPB;
  const int t  = threadIdx.x;

  __shared__ __align__(16) float sx[3432];       // 70ch x 49 (+gap at 147)
  __shared__ __align__(16) float pool_lo[1120];  // [4][70][4]: k=0..3, 16B rows
  __shared__ __align__(16) float pool_hi[1120];  // [4][70][4]: k=4..6 (+pad)
  __shared__ float gch[448];                     // [64][7]
  __shared__ float gcw[448];
  __shared__ __align__(16) float s_w[112];       // [2][7][8] weights, q-padded
  __shared__ float s_ghw[49];

  const int conv = t & 1, i2 = (t >> 1) & 1, cl = t >> 2;
  const int bi = 1 + conv;
  const float cb0 = cb[0];
  const float sc_bn = bnw[bi] * rsqrtf(bnrv[bi] + 1e-5f);
  const float rm_bn = bnrm[bi];
  const float sh_bn = bnb[bi];

  // ---- phase 0: stage ----
  if (t < 112) {
    int i2w = t / 56, rem = t % 56, p = rem / 8, q = rem % 8;
    s_w[t] = (q < 7) ? cw[i2w * 49 + p * 7 + q] : 0.f;
  }
  if (t < HW_) s_ghw[t] = ghw[n * HW_ + t];
  for (int i = t; i < 2 * 3 * HW_; i += 256) {   // halo channels first (latency)
    int side = i / 147, off = i % 147;
    int lc = side ? (67 + off / HW_) : (off / HW_);
    int c = c0 - 3 + lc;
    float vv = 0.f;
    if (c >= 0 && c < C_) vv = x[((size_t)n * C_ + c) * HW_ + off % HW_];
    sx[CHB(lc) + off % HW_] = vv;
  }
  const float4* xv = (const float4*)(x + ((size_t)n * C_ + c0) * HW_);
  float4* sxv = (float4*)(sx + 148);
  for (int v = t; v < 784; v += 256) sxv[v] = xv[v];
  __syncthreads();

  // ---- phase 1: W-pools / H-pools for all 70 local channels ----
  for (int i = t; i < 70 * 7; i += 256) {
    int lc = i / 7, k = i % 7;
    int base = CHB(lc);
    float s1 = 0.f, m1 = -3.4e38f, s2 = 0.f, m2 = -3.4e38f;
    #pragma unroll
    for (int j = 0; j < 7; ++j) {
      float a = sx[base + k * 7 + j];   // h=k, vary w  -> W-reduction (g_ch input)
      s1 += a; m1 = fmaxf(m1, a);
      float b = sx[base + j * 7 + k];   // w=k, vary h  -> H-reduction (g_cw input)
      s2 += b; m2 = fmaxf(m2, b);
    }
    float* pb = (k < 4) ? pool_lo : pool_hi;
    int kk = k & 3;
    pb[(0 * 70 + lc) * 4 + kk] = s1 * (1.f / 7.f);  // f=0: conv0 mean
    pb[(1 * 70 + lc) * 4 + kk] = m1;                // f=1: conv0 max
    pb[(2 * 70 + lc) * 4 + kk] = s2 * (1.f / 7.f);  // f=2: conv1 mean
    pb[(3 * 70 + lc) * 4 + kk] = m2;                // f=3: conv1 max
  }
  __syncthreads();

  // ---- phase 2: conv via b128 rows; thread = (conv, i2, cl) ----
  {
    const int f = conv * 2 + i2;
    const float* Wb = s_w + i2 * 56;                 // [7][8]
    float acc[7] = {0.f, 0.f, 0.f, 0.f, 0.f, 0.f, 0.f};
    #pragma unroll
    for (int p = 0; p < 7; ++p) {
      int ri = (f * 70 + cl + p) * 4;
      float4 r0 = *(const float4*)(pool_lo + ri);    // k = 0..3
      float4 r1 = *(const float4*)(pool_hi + ri);    // k = 4..6 (+pad)
      float row[7] = {r0.x, r0.y, r0.z, r0.w, r1.x, r1.y, r1.z};
      float4 w0 = *(const float4*)(Wb + p * 8);      // broadcast b128
      float4 w1 = *(const float4*)(Wb + p * 8 + 4);
      float wr[7] = {w0.x, w0.y, w0.z, w0.w, w1.x, w1.y, w1.z};
      #pragma unroll
      for (int q = 0; q < 7; ++q) {
        #pragma unroll
        for (int k = 0; k < 7; ++k) {
          int c = k + q - 3;                 // compile-time after unroll
          if (c >= 0 && c < 7) acc[k] += row[c] * wr[q];
        }
      }
    }
    float fsum[7];
    #pragma unroll
    for (int k = 0; k < 7; ++k) fsum[k] = acc[k] + __shfl_xor(acc[k], 2, 64);
    if (i2 == 0) {
      float* gp = (conv ? gcw : gch) + cl * 7;
      #pragma unroll
      for (int k = 0; k < 7; ++k) {
        float y = (fsum[k] + cb0 - rm_bn) * sc_bn + sh_bn;
        y = fmaxf(y, 0.f);
        gp[k] = 1.f / (1.f + __expf(-y));
      }
    }
  }
  __syncthreads();

  // ---- phase 3: fused multiply, LDS re-read (b128), float4 stores ----
  float4* outv = (float4*)(out + ((size_t)n * C_ + c0) * HW_);
  for (int v = t; v < 784; v += 256) {
    float4 q = sxv[v];
    int e0 = v * 4;
    int cj = e0 / 49;
    int hw0 = e0 - cj * 49;
    float r0 = q.x, r1 = q.y, r2 = q.z, r3 = q.w;
    {
      int hw = hw0;
      int cjj = cj + (hw >= 49); hw -= (hw >= 49) ? 49 : 0;
      int h = (hw * 37) >> 8, w2 = hw - h * 7;
      r0 *= (s_ghw[hw] + gch[cjj * 7 + h] + gcw[cjj * 7 + w2]) * (1.f / 3.f);
    }
    {
      int hw = hw0 + 1;
      int cjj = cj + (hw >= 49); hw -= (hw >= 49) ? 49 : 0;
      int h = (hw * 37) >> 8, w2 = hw - h * 7;
      r1 *= (s_ghw[hw] + gch[cjj * 7 + h] + gcw[cjj * 7 + w2]) * (1.f / 3.f);
    }
    {
      int hw = hw0 + 2;
      int cjj = cj + (hw >= 49); hw -= (hw >= 49) ? 49 : 0;
      int h = (hw * 37) >> 8, w2 = hw - h * 7;
      r2 *= (s_ghw[hw] + gch[cjj * 7 + h] + gcw[cjj * 7 + w2]) * (1.f / 3.f);
    }
    {
      int hw = hw0 + 3;
      int cjj = cj + (hw >= 49); hw -= (hw >= 49) ? 49 : 0;
      int h = (hw * 37) >> 8, w2 = hw - h * 7;
      r3 *= (s_ghw[hw] + gch[cjj * 7 + h] + gcw[cjj * 7 + w2]) * (1.f / 3.f);
    }
    outv[v] = make_float4(r0, r1, r2, r3);
  }
}

extern "C" void kernel_launch(void* const* d_in, const int* in_sizes, int n_in,
                              void* d_out, int out_size, void* d_ws, size_t ws_size,
                              hipStream_t stream) {
  const float* x    = (const float*)d_in[0];
  const float* cw   = (const float*)d_in[1];
  const float* cb   = (const float*)d_in[2];
  const float* bnw  = (const float*)d_in[3];
  const float* bnb  = (const float*)d_in[4];
  const float* bnrm = (const float*)d_in[5];
  const float* bnrv = (const float*)d_in[6];
  float* out = (float*)d_out;

  float* psum = (float*)d_ws;                         // N*8*49
  float* pmax = psum + (size_t)N_ * NCHUNK * HW_;     // N*8*49
  float* ghw  = pmax + (size_t)N_ * NCHUNK * HW_;     // N*49

  k_poolc<<<dim3(NCHUNK, N_), 256, 0, stream>>>(x, psum, pmax);
  k_ghw<<<dim3(N_), 64, 0, stream>>>(psum, pmax, cw, cb, bnw, bnb, bnrm, bnrv, ghw);
  k_main<<<dim3(NCC, N_), 256, 0, stream>>>(x, ghw, cw, cb, bnw, bnb, bnrm, bnrv, out);
}